// Round 2
// baseline (47.656 us; speedup 1.0000x reference)
//
#include <hip/hip_runtime.h>
#include <hip/hip_bf16.h>

#define D_ 128
#define S_ 512
#define B_ 4
#define H_ 8

typedef short bf16x8 __attribute__((ext_vector_type(8)));
typedef float f32x4 __attribute__((ext_vector_type(4)));

__device__ __forceinline__ short f2bf(float f) {
  __hip_bfloat16 h = __float2bfloat16(f);
  return __builtin_bit_cast(short, h);
}

__device__ __forceinline__ float fsigmoid(float x) {
  return __builtin_amdgcn_rcpf(1.0f + __expf(-x));
}

// Kernel P: A[row][e] = sum_k x[row][k]*w1[k][e] + b1[e]
//           C[row][e] = sum_k x[row][k]*w1[128+k][e]
// rows = B*S = 2048. Grid 512 blocks x 256 thr, 4 rows/block.
__global__ __launch_bounds__(256)
void proj_kernel(const float* __restrict__ x, const float* __restrict__ w1,
                 const float* __restrict__ b1, float* __restrict__ Aq,
                 float* __restrict__ Cq) {
  __shared__ float xs[4 * D_];
  const int t = threadIdx.x;
  const int row0 = blockIdx.x * 4;
  ((float2*)xs)[t] = ((const float2*)(x + row0 * D_))[t];
  __syncthreads();
  const int e4 = (t & 31) * 4;      // output col group (0..124)
  const int half = (t >> 5) & 1;    // 0 -> A (w1[:128]), 1 -> C (w1[128:])
  const int r = t >> 6;             // row within block (0..3), wave-uniform
  const float* w1p = w1 + half * D_ * D_ + e4;
  const float* xr = xs + r * D_;
  float4 acc = {0.f, 0.f, 0.f, 0.f};
  #pragma unroll 8
  for (int k = 0; k < D_; ++k) {
    float4 wv = *(const float4*)(w1p + k * D_);
    float xv = xr[k];
    acc.x += xv * wv.x; acc.y += xv * wv.y;
    acc.z += xv * wv.z; acc.w += xv * wv.w;
  }
  const int row = row0 + r;
  if (half == 0) {
    float4 bv = *(const float4*)(b1 + e4);
    acc.x += bv.x; acc.y += bv.y; acc.z += bv.z; acc.w += bv.w;
    *(float4*)(Aq + row * D_ + e4) = acc;
  } else {
    *(float4*)(Cq + row * D_ + e4) = acc;
  }
}

// Kernel E: per block = (b, 4 consecutive i). Wave w owns i0+w.
// Loop over 32 j-tiles of 16: stage C-tile in LDS, form H = relu(a+c) bf16
// fragments, MFMA 16x16x32 against w2 (N=16, h<8 real), sigmoid, store.
// MFMA A layout: row = lane&15, k = 8*(lane>>4)+e.
// MFMA D layout: col = lane&15, row = (lane>>4)*4 + reg.
__global__ __launch_bounds__(256)
void edge_kernel(const float* __restrict__ Aq, const float* __restrict__ Cq,
                 const float* __restrict__ w2, const float* __restrict__ b2,
                 float* __restrict__ out) {
  __shared__ float cs[16 * 132];     // +4 pad words per row -> 2-way banks (free)
  const int t = threadIdx.x;
  const int lane = t & 63;
  const int wid = t >> 6;                  // 0..3
  const int b = blockIdx.x >> 7;           // /128
  const int i = (blockIdx.x & 127) * 4 + wid;
  const int jcol = lane & 15;              // A-row (j in tile) == B/D col (h)
  const int lgrp = lane >> 4;              // k-group 0..3

  // a registers (b1 already folded in): d = ch*32 + lgrp*8 + e
  float areg[32];
  {
    const float* Ai = Aq + (b * S_ + i) * D_ + lgrp * 8;
    #pragma unroll
    for (int ch = 0; ch < 4; ++ch) {
      float4 v0 = *(const float4*)(Ai + ch * 32);
      float4 v1 = *(const float4*)(Ai + ch * 32 + 4);
      areg[ch*8+0] = v0.x; areg[ch*8+1] = v0.y;
      areg[ch*8+2] = v0.z; areg[ch*8+3] = v0.w;
      areg[ch*8+4] = v1.x; areg[ch*8+5] = v1.y;
      areg[ch*8+6] = v1.z; areg[ch*8+7] = v1.w;
    }
  }
  // w2 B-fragments: B[k][h], lane holds col h=jcol, k = ch*32+lgrp*8+e
  bf16x8 w2f[4];
  #pragma unroll
  for (int ch = 0; ch < 4; ++ch) {
    #pragma unroll
    for (int e = 0; e < 8; ++e) {
      float wv = (jcol < H_) ? w2[(ch * 32 + lgrp * 8 + e) * H_ + jcol] : 0.0f;
      w2f[ch][e] = f2bf(wv);
    }
  }
  const float b2v = (jcol < H_) ? b2[jcol] : 0.0f;

  float* outp = out + (((size_t)(b * H_ + (jcol & 7)) * S_ + i) * S_) + lgrp * 4;

  const int crow = t >> 4;            // staging row 0..15
  const int cd8 = (t & 15) * 8;       // staging d offset
  const float* cstage = Cq + (b * S_ + crow) * D_ + cd8;
  float* lstage = cs + crow * 132 + cd8;
  const float* cread = cs + jcol * 132 + lgrp * 8;

  for (int jt = 0; jt < 32; ++jt) {
    {   // stage C j-tile [16][128] -> LDS [16][132]
      const float* cp = cstage + jt * 16 * D_;
      float4 c0 = *(const float4*)cp;
      float4 c1 = *(const float4*)(cp + 4);
      *(float4*)lstage = c0;
      *(float4*)(lstage + 4) = c1;
    }
    __syncthreads();
    f32x4 acc = {0.f, 0.f, 0.f, 0.f};
    #pragma unroll
    for (int ch = 0; ch < 4; ++ch) {
      float4 c0 = *(const float4*)(cread + ch * 32);
      float4 c1 = *(const float4*)(cread + ch * 32 + 4);
      float h0 = fmaxf(c0.x + areg[ch*8+0], 0.f);
      float h1 = fmaxf(c0.y + areg[ch*8+1], 0.f);
      float h2 = fmaxf(c0.z + areg[ch*8+2], 0.f);
      float h3 = fmaxf(c0.w + areg[ch*8+3], 0.f);
      float h4 = fmaxf(c1.x + areg[ch*8+4], 0.f);
      float h5 = fmaxf(c1.y + areg[ch*8+5], 0.f);
      float h6 = fmaxf(c1.z + areg[ch*8+6], 0.f);
      float h7 = fmaxf(c1.w + areg[ch*8+7], 0.f);
      bf16x8 hf;
      hf[0]=f2bf(h0); hf[1]=f2bf(h1); hf[2]=f2bf(h2); hf[3]=f2bf(h3);
      hf[4]=f2bf(h4); hf[5]=f2bf(h5); hf[6]=f2bf(h6); hf[7]=f2bf(h7);
      acc = __builtin_amdgcn_mfma_f32_16x16x32_bf16(hf, w2f[ch], acc, 0, 0, 0);
    }
    __syncthreads();
    if (jcol < H_) {
      float4 o;
      o.x = fsigmoid(acc[0] + b2v);
      o.y = fsigmoid(acc[1] + b2v);
      o.z = fsigmoid(acc[2] + b2v);
      o.w = fsigmoid(acc[3] + b2v);
      *(float4*)(outp + jt * 16) = o;
    }
  }
}

extern "C" void kernel_launch(void* const* d_in, const int* in_sizes, int n_in,
                              void* d_out, int out_size, void* d_ws, size_t ws_size,
                              hipStream_t stream) {
  const float* x  = (const float*)d_in[0];
  const float* w1 = (const float*)d_in[1];
  const float* b1 = (const float*)d_in[2];
  const float* w2 = (const float*)d_in[3];
  const float* b2 = (const float*)d_in[4];
  float* out = (float*)d_out;
  float* Aq = (float*)d_ws;                 // 2048*128 f32 = 1 MB
  float* Cq = Aq + B_ * S_ * D_;            // +1 MB (ws needs 2 MB)
  proj_kernel<<<(B_ * S_) / 4, 256, 0, stream>>>(x, w1, b1, Aq, Cq);
  edge_kernel<<<(B_ * S_) / 4, 256, 0, stream>>>(Aq, Cq, w2, b2, out);
}

// Round 3
// 39.719 us; speedup vs baseline: 1.1998x; 1.1998x over previous
//
#include <hip/hip_runtime.h>
#include <hip/hip_bf16.h>

#define D_ 128
#define S_ 512
#define B_ 4
#define H_ 8

typedef short bf16x8 __attribute__((ext_vector_type(8)));
typedef float f32x4 __attribute__((ext_vector_type(4)));

__device__ __forceinline__ short f2bf(float f) {
  __hip_bfloat16 h = __float2bfloat16(f);
  return __builtin_bit_cast(short, h);
}
__device__ __forceinline__ float bf2f(short s) {
  unsigned u = ((unsigned)(unsigned short)s) << 16;
  return __builtin_bit_cast(float, u);
}
__device__ __forceinline__ float fsigmoid(float x) {
  return __builtin_amdgcn_rcpf(1.0f + __expf(-x));
}

// Proj v2: A[row][e]=x[row]@w1[:D]+b1, C[row][e]=x[row]@w1[D:].
// 512 blocks x 256 thr, 4 rows/block, k-quarter split so w1 is read
// EXACTLY once per block (64 MB total, was 256 MB).
__global__ __launch_bounds__(256)
void proj_kernel(const float* __restrict__ x, const float* __restrict__ w1,
                 const float* __restrict__ b1, float* __restrict__ Aq,
                 float* __restrict__ Cq) {
  __shared__ float xs[4 * D_];
  __shared__ f32x4 red[256][5];   // [5] pad: reduce-read stride 5 -> all 8 16B slots
  const int t = threadIdx.x;
  const int row0 = blockIdx.x * 4;
  ((float2*)xs)[t] = ((const float2*)(x + row0 * D_))[t];
  __syncthreads();
  const int combo = t & 63;            // (e4, half)
  const int e4 = (combo & 31) * 4;
  const int half = combo >> 5;
  const int kq = t >> 6;               // k-quarter, wave-uniform
  const float* w1p = w1 + (half * D_ + kq * 32) * D_ + e4;
  const float* xq = xs + kq * 32;
  f32x4 acc[4] = {};
  #pragma unroll 8
  for (int k = 0; k < 32; ++k) {
    float4 wv = *(const float4*)(w1p + k * D_);
    #pragma unroll
    for (int r = 0; r < 4; ++r) {
      float xv = xq[r * D_ + k];
      acc[r][0] += xv * wv.x; acc[r][1] += xv * wv.y;
      acc[r][2] += xv * wv.z; acc[r][3] += xv * wv.w;
    }
  }
  #pragma unroll
  for (int r = 0; r < 4; ++r) red[t][r] = acc[r];
  __syncthreads();
  // thread u -> (row r, combo c2); sum the 4 k-quarters
  const int r = t >> 6;
  const int c2 = t & 63;
  f32x4 s = red[c2][r];
  #pragma unroll
  for (int q = 1; q < 4; ++q) {
    f32x4 v = red[c2 + 64 * q][r];
    s[0] += v[0]; s[1] += v[1]; s[2] += v[2]; s[3] += v[3];
  }
  const int fe4 = (c2 & 31) * 4;
  const int row = row0 + r;
  if ((c2 >> 5) == 0) {
    float4 bv = *(const float4*)(b1 + fe4);
    s[0] += bv.x; s[1] += bv.y; s[2] += bv.z; s[3] += bv.w;
    *(f32x4*)(Aq + row * D_ + fe4) = s;
  } else {
    *(f32x4*)(Cq + row * D_ + fe4) = s;
  }
}

// Edge v3: block = (b, 8 consecutive i), 8 waves, wave w owns i0+w.
// Stage ALL of C[b] (512x128) as bf16 into 128KB LDS once (XOR-swizzled
// 16B units: u' = u ^ (row&7) -> conflict-free fragment reads), single
// __syncthreads, then a barrier-free main loop over 32 j-tiles:
// 4x ds_read_b128 -> relu(a+c) bf16 frags -> 4x MFMA 16x16x32 -> sigmoid store.
// MFMA A layout: row = lane&15 (=j), k = 8*(lane>>4)+e (verified r2).
// MFMA D layout: col = lane&15 (=h), row = (lane>>4)*4 + reg (=j offset).
__global__ __launch_bounds__(512)
void edge_kernel(const float* __restrict__ Aq, const float* __restrict__ Cq,
                 const float* __restrict__ w2, const float* __restrict__ b2,
                 float* __restrict__ out) {
  __shared__ short cbf[S_ * D_];       // 128 KB bf16, swizzled
  const int t = threadIdx.x;
  const int lane = t & 63;
  const int wid = t >> 6;              // 0..7
  const int b = blockIdx.x >> 6;
  const int i = (blockIdx.x & 63) * 8 + wid;

  // ---- stage C[b] -> bf16 LDS (8192 16B-units / 512 threads = 16 iters)
  {
    const float* cb = Cq + b * (S_ * D_);
    #pragma unroll 4
    for (int it = 0; it < 16; ++it) {
      int p = t + it * 512;            // unit index
      int row = p >> 4;
      int u = p & 15;
      const float* src = cb + row * D_ + u * 8;
      float4 v0 = *(const float4*)src;
      float4 v1 = *(const float4*)(src + 4);
      bf16x8 w;
      w[0] = f2bf(v0.x); w[1] = f2bf(v0.y); w[2] = f2bf(v0.z); w[3] = f2bf(v0.w);
      w[4] = f2bf(v1.x); w[5] = f2bf(v1.y); w[6] = f2bf(v1.z); w[7] = f2bf(v1.w);
      int up = u ^ (row & 7);
      *(bf16x8*)(cbf + row * D_ + up * 8) = w;
    }
  }

  const int jcol = lane & 15;          // j within tile == output h (B/D col)
  const int lgrp = lane >> 4;          // k-group

  // a registers (b1 folded in): d = ch*32 + lgrp*8 + e
  float areg[32];
  {
    const float* Ai = Aq + (b * S_ + i) * D_ + lgrp * 8;
    #pragma unroll
    for (int ch = 0; ch < 4; ++ch) {
      float4 v0 = *(const float4*)(Ai + ch * 32);
      float4 v1 = *(const float4*)(Ai + ch * 32 + 4);
      areg[ch*8+0] = v0.x; areg[ch*8+1] = v0.y;
      areg[ch*8+2] = v0.z; areg[ch*8+3] = v0.w;
      areg[ch*8+4] = v1.x; areg[ch*8+5] = v1.y;
      areg[ch*8+6] = v1.z; areg[ch*8+7] = v1.w;
    }
  }
  // w2 B-fragments: lane holds col h=jcol, k = ch*32 + lgrp*8 + e
  bf16x8 w2f[4];
  #pragma unroll
  for (int ch = 0; ch < 4; ++ch) {
    #pragma unroll
    for (int e = 0; e < 8; ++e) {
      float wv = (jcol < H_) ? w2[(ch * 32 + lgrp * 8 + e) * H_ + jcol] : 0.0f;
      w2f[ch][e] = f2bf(wv);
    }
  }
  const float b2v = (jcol < H_) ? b2[jcol] : 0.0f;
  float* outp = out + (((size_t)(b * H_ + (jcol & 7)) * S_ + i) * S_) + lgrp * 4;

  __syncthreads();                     // the only barrier

  for (int jt = 0; jt < 32; ++jt) {
    const int row = jt * 16 + jcol;
    const short* base = cbf + row * D_;
    const int sw = jcol & 7;           // == row & 7
    f32x4 acc = {0.f, 0.f, 0.f, 0.f};
    #pragma unroll
    for (int ch = 0; ch < 4; ++ch) {
      int up = (ch * 4 + lgrp) ^ sw;
      bf16x8 cv = *(const bf16x8*)(base + up * 8);
      bf16x8 hf;
      #pragma unroll
      for (int e = 0; e < 8; ++e)
        hf[e] = f2bf(fmaxf(bf2f(cv[e]) + areg[ch*8+e], 0.f));
      acc = __builtin_amdgcn_mfma_f32_16x16x32_bf16(hf, w2f[ch], acc, 0, 0, 0);
    }
    if (jcol < H_) {
      float4 o;
      o.x = fsigmoid(acc[0] + b2v);
      o.y = fsigmoid(acc[1] + b2v);
      o.z = fsigmoid(acc[2] + b2v);
      o.w = fsigmoid(acc[3] + b2v);
      *(float4*)(outp + jt * 16) = o;
    }
  }
}

extern "C" void kernel_launch(void* const* d_in, const int* in_sizes, int n_in,
                              void* d_out, int out_size, void* d_ws, size_t ws_size,
                              hipStream_t stream) {
  const float* x  = (const float*)d_in[0];
  const float* w1 = (const float*)d_in[1];
  const float* b1 = (const float*)d_in[2];
  const float* w2 = (const float*)d_in[3];
  const float* b2 = (const float*)d_in[4];
  float* out = (float*)d_out;
  float* Aq = (float*)d_ws;                 // 2048*128 f32 = 1 MB
  float* Cq = Aq + B_ * S_ * D_;            // +1 MB
  proj_kernel<<<(B_ * S_) / 4, 256, 0, stream>>>(x, w1, b1, Aq, Cq);
  edge_kernel<<<B_ * 64, 512, 0, stream>>>(Aq, Cq, w2, b2, out);
}

// Round 4
// 37.854 us; speedup vs baseline: 1.2589x; 1.0493x over previous
//
#include <hip/hip_runtime.h>
#include <hip/hip_bf16.h>

#define D_ 128
#define S_ 512
#define B_ 4
#define H_ 8

typedef short bf16x8 __attribute__((ext_vector_type(8)));
typedef float f32x4 __attribute__((ext_vector_type(4)));
typedef float f32x2 __attribute__((ext_vector_type(2)));

__device__ __forceinline__ short f2bf(float f) {
  __hip_bfloat16 h = __float2bfloat16(f);
  return __builtin_bit_cast(short, h);
}
__device__ __forceinline__ float bf2f(short s) {
  unsigned u = ((unsigned)(unsigned short)s) << 16;
  return __builtin_bit_cast(float, u);
}
__device__ __forceinline__ float fsigmoid(float x) {
  return __builtin_amdgcn_rcpf(1.0f + __expf(-x));
}

// Proj v2 (unchanged from round 3): A=x@w1[:D]+b1, C=x@w1[D:].
// 512 blocks x 256 thr, 4 rows/block, k-quarter split; w1 read once/block.
__global__ __launch_bounds__(256)
void proj_kernel(const float* __restrict__ x, const float* __restrict__ w1,
                 const float* __restrict__ b1, float* __restrict__ Aq,
                 float* __restrict__ Cq) {
  __shared__ float xs[4 * D_];
  __shared__ f32x4 red[256][5];
  const int t = threadIdx.x;
  const int row0 = blockIdx.x * 4;
  ((float2*)xs)[t] = ((const float2*)(x + row0 * D_))[t];
  __syncthreads();
  const int combo = t & 63;
  const int e4 = (combo & 31) * 4;
  const int half = combo >> 5;
  const int kq = t >> 6;
  const float* w1p = w1 + (half * D_ + kq * 32) * D_ + e4;
  const float* xq = xs + kq * 32;
  f32x4 acc[4] = {};
  #pragma unroll 8
  for (int k = 0; k < 32; ++k) {
    float4 wv = *(const float4*)(w1p + k * D_);
    #pragma unroll
    for (int r = 0; r < 4; ++r) {
      float xv = xq[r * D_ + k];
      acc[r][0] += xv * wv.x; acc[r][1] += xv * wv.y;
      acc[r][2] += xv * wv.z; acc[r][3] += xv * wv.w;
    }
  }
  #pragma unroll
  for (int r = 0; r < 4; ++r) red[t][r] = acc[r];
  __syncthreads();
  const int r = t >> 6;
  const int c2 = t & 63;
  f32x4 s = red[c2][r];
  #pragma unroll
  for (int q = 1; q < 4; ++q) {
    f32x4 v = red[c2 + 64 * q][r];
    s[0] += v[0]; s[1] += v[1]; s[2] += v[2]; s[3] += v[3];
  }
  const int fe4 = (c2 & 31) * 4;
  const int row = row0 + r;
  if ((c2 >> 5) == 0) {
    float4 bv = *(const float4*)(b1 + fe4);
    s[0] += bv.x; s[1] += bv.y; s[2] += bv.z; s[3] += bv.w;
    *(f32x4*)(Aq + row * D_ + fe4) = s;
  } else {
    *(f32x4*)(Cq + row * D_ + fe4) = s;
  }
}

// Edge v4: block = (b, i-group of 8, j-half of 256). 8 waves, wave w -> i.
// 64 KB LDS (bf16 C half, XOR-swizzled 16B units) -> 2 blocks/CU, 4 waves/SIMD.
// Main loop: 16 j-tiles, double-buffered ds_read prefetch, f32x2 packed
// H-formation, 4x MFMA 16x16x32, sigmoid, float4 store.
// MFMA A layout: row=lane&15 (=j), k=8*(lane>>4)+e. D: col=lane&15 (=h),
// row=(lane>>4)*4+reg (verified r2/r3, absmax 3.9e-3).
__global__ __launch_bounds__(512, 4)
void edge_kernel(const float* __restrict__ Aq, const float* __restrict__ Cq,
                 const float* __restrict__ w2, const float* __restrict__ b2,
                 float* __restrict__ out) {
  __shared__ short cbf[256 * D_];        // 64 KB
  const int t = threadIdx.x;
  const int lane = t & 63;
  const int wid = t >> 6;                // 0..7
  const int b  = blockIdx.x >> 7;
  const int jh = (blockIdx.x >> 6) & 1;  // j half
  const int ig = blockIdx.x & 63;
  const int i = ig * 8 + wid;

  // ---- stage C[b][jh*256 .. +255][:] -> bf16 LDS (4096 units / 512 thr)
  {
    const float* cb = Cq + (b * S_ + jh * 256) * D_;
    #pragma unroll
    for (int it = 0; it < 8; ++it) {
      int p = t + it * 512;
      int row = p >> 4;
      int u = p & 15;
      const float* src = cb + row * D_ + u * 8;
      float4 v0 = *(const float4*)src;
      float4 v1 = *(const float4*)(src + 4);
      bf16x8 w;
      w[0] = f2bf(v0.x); w[1] = f2bf(v0.y); w[2] = f2bf(v0.z); w[3] = f2bf(v0.w);
      w[4] = f2bf(v1.x); w[5] = f2bf(v1.y); w[6] = f2bf(v1.z); w[7] = f2bf(v1.w);
      *(bf16x8*)(cbf + row * D_ + (u ^ (row & 7)) * 8) = w;
    }
  }

  const int jcol = lane & 15;            // j within tile == output h
  const int lgrp = lane >> 4;            // k-group
  const int sw = jcol & 7;               // == row&7 for this lane's rows

  // a registers as packed f32x2 (b1 folded): d = ch*32 + lgrp*8 + 2p (+0/1)
  f32x2 apk[4][4];
  {
    const float* Ai = Aq + (b * S_ + i) * D_ + lgrp * 8;
    #pragma unroll
    for (int ch = 0; ch < 4; ++ch) {
      float4 v0 = *(const float4*)(Ai + ch * 32);
      float4 v1 = *(const float4*)(Ai + ch * 32 + 4);
      apk[ch][0][0] = v0.x; apk[ch][0][1] = v0.y;
      apk[ch][1][0] = v0.z; apk[ch][1][1] = v0.w;
      apk[ch][2][0] = v1.x; apk[ch][2][1] = v1.y;
      apk[ch][3][0] = v1.z; apk[ch][3][1] = v1.w;
    }
  }
  // w2 B-fragments: lane holds col h=jcol, k = ch*32 + lgrp*8 + e
  bf16x8 w2f[4];
  #pragma unroll
  for (int ch = 0; ch < 4; ++ch) {
    #pragma unroll
    for (int e = 0; e < 8; ++e) {
      float wv = (jcol < H_) ? w2[(ch * 32 + lgrp * 8 + e) * H_ + jcol] : 0.0f;
      w2f[ch][e] = f2bf(wv);
    }
  }
  const float b2v = (jcol < H_) ? b2[jcol] : 0.0f;
  float* outp = out + (((size_t)(b * H_ + (jcol & 7)) * S_ + i) * S_)
                + jh * 256 + lgrp * 4;

  __syncthreads();                       // only barrier

  bf16x8 cva[4], cvb[4];
  auto LOADT = [&](bf16x8 (&dst)[4], int jt) {
    const short* bp = cbf + (jt * 16 + jcol) * D_;
    #pragma unroll
    for (int ch = 0; ch < 4; ++ch)
      dst[ch] = *(const bf16x8*)(bp + (((ch * 4 + lgrp) ^ sw) * 8));
  };
  auto COMPUTE = [&](bf16x8 (&cv)[4], int jt) {
    f32x4 acc = {0.f, 0.f, 0.f, 0.f};
    #pragma unroll
    for (int ch = 0; ch < 4; ++ch) {
      bf16x8 hf;
      #pragma unroll
      for (int p = 0; p < 4; ++p) {
        f32x2 v;
        v[0] = bf2f(cv[ch][2 * p]);
        v[1] = bf2f(cv[ch][2 * p + 1]);
        v += apk[ch][p];                 // v_pk_add_f32
        hf[2 * p]     = f2bf(fmaxf(v[0], 0.f));
        hf[2 * p + 1] = f2bf(fmaxf(v[1], 0.f));
      }
      acc = __builtin_amdgcn_mfma_f32_16x16x32_bf16(hf, w2f[ch], acc, 0, 0, 0);
    }
    if (jcol < H_) {
      float4 o;
      o.x = fsigmoid(acc[0] + b2v);
      o.y = fsigmoid(acc[1] + b2v);
      o.z = fsigmoid(acc[2] + b2v);
      o.w = fsigmoid(acc[3] + b2v);
      *(float4*)(outp + jt * 16) = o;
    }
  };

  LOADT(cva, 0);
  #pragma unroll 1
  for (int jt = 0; jt < 16; jt += 2) {
    LOADT(cvb, jt + 1);                  // prefetch tile jt+1
    COMPUTE(cva, jt);
    LOADT(cva, (jt + 2) & 15);           // prefetch tile jt+2 (wrap harmless)
    COMPUTE(cvb, jt + 1);
  }
}

extern "C" void kernel_launch(void* const* d_in, const int* in_sizes, int n_in,
                              void* d_out, int out_size, void* d_ws, size_t ws_size,
                              hipStream_t stream) {
  const float* x  = (const float*)d_in[0];
  const float* w1 = (const float*)d_in[1];
  const float* b1 = (const float*)d_in[2];
  const float* w2 = (const float*)d_in[3];
  const float* b2 = (const float*)d_in[4];
  float* out = (float*)d_out;
  float* Aq = (float*)d_ws;                 // 2048*128 f32 = 1 MB
  float* Cq = Aq + B_ * S_ * D_;            // +1 MB
  proj_kernel<<<(B_ * S_) / 4, 256, 0, stream>>>(x, w1, b1, Aq, Cq);
  edge_kernel<<<B_ * 2 * 64, 512, 0, stream>>>(Aq, Cq, w2, b2, out);
}